// Round 2
// baseline (707.953 us; speedup 1.0000x reference)
//
#include <hip/hip_runtime.h>
#include <hip/hip_bf16.h>

// Problem constants
#define NB    16          // batch
#define NPIX  4096        // 64*64 pixels per batch
#define PTOT  65536       // NB*NPIX
#define CDIM  256
#define NHEAD 4
#define SCALE 0.125f      // 1/sqrt(64)

__device__ __forceinline__ float leaky(float x, float a) { return x > 0.f ? x : a * x; }

// ---------------------------------------------------------------------------
// Kernel 1: style path (tiny). One block per n, 256 threads (thread = channel).
// Produces: acq[n][c] = 4096 * sum_d qc[n,d] * W_ch[d,c]   (channel-attn q-part)
//           qpos[n][m] = sum_d qp[n,d] * W_pos[d,m]         (pos-attn q-part)
// ---------------------------------------------------------------------------
__global__ __launch_bounds__(256) void k1_style(
    const float* __restrict__ style, const float* __restrict__ W_dense,
    const float* __restrict__ Wq_c, const float* __restrict__ gq_c, const float* __restrict__ bq_c,
    const float* __restrict__ Wq_p, const float* __restrict__ gq_p, const float* __restrict__ bq_p,
    const float* __restrict__ W_ch, const float* __restrict__ W_pos,
    float* __restrict__ acq, float* __restrict__ qpos)
{
    __shared__ float s0[256], s1[256], qc_s[256], qp_s[256];
    const int n = blockIdx.x, t = threadIdx.x;
    s0[t] = style[n * 256 + t];
    __syncthreads();
    float acc = 0.f;
    for (int k = 0; k < 256; ++k) acc += s0[k] * W_dense[k * 256 + t];
    s1[t] = leaky(acc, 0.3f);          // Keras LeakyReLU default alpha on Dense
    __syncthreads();
    float aq = 0.f, ap = 0.f;
    for (int k = 0; k < 256; ++k) {
        const float q = s1[k];
        aq += q * Wq_c[k * 256 + t];
        ap += q * Wq_p[k * 256 + t];
    }
    qc_s[t] = leaky(aq * gq_c[t] + bq_c[t], 0.1f);
    qp_s[t] = leaky(ap * gq_p[t] + bq_p[t], 0.1f);
    __syncthreads();
    float a = 0.f;
    for (int d = 0; d < 256; ++d) a += qc_s[d] * W_ch[d * 256 + t];
    acq[n * 256 + t] = 4096.f * a;
    if (t < 4) {
        float s = 0.f;
        for (int d = 0; d < 256; ++d) s += qp_s[d] * W_pos[d * 4 + t];
        qpos[n * 4 + t] = s;
    }
}

// ---------------------------------------------------------------------------
// Kernel 2: big 1x1-conv GEMM  [64 pixels x 256 cols] per block, K=256.
// 256 threads, 8x8 micro-tile (cx in [0,32) -> cols j*32+cx, py in [0,8) -> 8 pixels).
// Epilogue by template G:
//   G=0 (kc): reduce post-activation over the 64 pixels -> partial[blk][256]
//   G=1 (vc): store bf16
//   G=2 (kp): contract with W_pos bottom -> 4 logits/pixel (incl. q-part, scaled)
//   G=3 (vp): store bf16
// ---------------------------------------------------------------------------
template<int G>
__global__ __launch_bounds__(256) void k2_gemm(
    const float* __restrict__ A,       // inputs [65536][256]
    const float* __restrict__ B,       // weight [256][256]
    const float* __restrict__ gvec, const float* __restrict__ bvec,
    const float* __restrict__ W_pos,   // G==2 only
    const float* __restrict__ qpos,    // G==2 only
    float* __restrict__ out_f,         // G0: partial[1024][256]; G2: logits[65536][4]
    __hip_bfloat16* __restrict__ out_b) // G1/G3: v [65536][256] bf16
{
    __shared__ float Asb[16][68];      // pad 68: 16B-aligned rows, 2-way-max bank conflict
    __shared__ float Bs[16][256];
    __shared__ float red[8][256];      // G0 cross-py reduce
    __shared__ float wpos_s[256][4];   // G2

    const int t  = threadIdx.x;
    const int cx = t & 31, py = t >> 5;
    const int pix0 = blockIdx.x * 64;

    if constexpr (G == 2) {
        for (int q = 0; q < 4; ++q) {
            const int e = t + q * 256;           // e in [0,1024)
            wpos_s[e >> 2][e & 3] = W_pos[(256 + (e >> 2)) * 4 + (e & 3)];
        }
    }

    float acc[8][8];
#pragma unroll
    for (int i = 0; i < 8; ++i)
#pragma unroll
        for (int j = 0; j < 8; ++j) acc[i][j] = 0.f;

    for (int k0 = 0; k0 < 256; k0 += 16) {
        __syncthreads();
#pragma unroll
        for (int q = 0; q < 4; ++q) {            // stage A: 64 rows x 16 k
            const int e = t + q * 256;
            const int r = e >> 4, kk = e & 15;
            Asb[kk][r] = A[(pix0 + r) * 256 + k0 + kk];
        }
#pragma unroll
        for (int rr = 0; rr < 16; ++rr)          // stage B: 16 rows x 256 cols
            Bs[rr][t] = B[(k0 + rr) * 256 + t];
        __syncthreads();
#pragma unroll
        for (int k = 0; k < 16; ++k) {
            float a[8], b[8];
            const float4* ap4 = reinterpret_cast<const float4*>(&Asb[k][py * 8]);
            const float4 a0 = ap4[0], a1 = ap4[1];
            a[0]=a0.x; a[1]=a0.y; a[2]=a0.z; a[3]=a0.w;
            a[4]=a1.x; a[5]=a1.y; a[6]=a1.z; a[7]=a1.w;
#pragma unroll
            for (int j = 0; j < 8; ++j) b[j] = Bs[k][j * 32 + cx];
#pragma unroll
            for (int i = 0; i < 8; ++i)
#pragma unroll
                for (int j = 0; j < 8; ++j) acc[i][j] += a[i] * b[j];
        }
    }

    // BN affine + LeakyReLU(0.1), in place
#pragma unroll
    for (int j = 0; j < 8; ++j) {
        const int col = j * 32 + cx;
        const float g = gvec[col], bb = bvec[col];
#pragma unroll
        for (int i = 0; i < 8; ++i) acc[i][j] = leaky(acc[i][j] * g + bb, 0.1f);
    }

    if constexpr (G == 1 || G == 3) {
#pragma unroll
        for (int i = 0; i < 8; ++i) {
            const int p = pix0 + py * 8 + i;
#pragma unroll
            for (int j = 0; j < 8; ++j)
                out_b[p * 256 + j * 32 + cx] = __float2bfloat16(acc[i][j]);
        }
    } else if constexpr (G == 0) {
#pragma unroll
        for (int j = 0; j < 8; ++j) {
            float s = 0.f;
#pragma unroll
            for (int i = 0; i < 8; ++i) s += acc[i][j];
            red[py][j * 32 + cx] = s;
        }
        __syncthreads();
        float tot = 0.f;
#pragma unroll
        for (int q = 0; q < 8; ++q) tot += red[q][t];
        out_f[blockIdx.x * 256 + t] = tot;       // partial ksum for this 64-pixel tile
    } else {                                      // G == 2
#pragma unroll
        for (int i = 0; i < 8; ++i) {
            float pm[4] = {0.f, 0.f, 0.f, 0.f};
#pragma unroll
            for (int j = 0; j < 8; ++j) {
                const int col = j * 32 + cx;
                const float v = acc[i][j];
#pragma unroll
                for (int m = 0; m < 4; ++m) pm[m] += v * wpos_s[col][m];
            }
#pragma unroll
            for (int m = 0; m < 4; ++m) {
                float v = pm[m];
#pragma unroll
                for (int mask = 16; mask >= 1; mask >>= 1) v += __shfl_xor(v, mask, 64);
                pm[m] = v;
            }
            if (cx == 0) {
                const int p = pix0 + py * 8 + i;
                const int n = p >> 12;
#pragma unroll
                for (int m = 0; m < 4; ++m)
                    out_f[p * 4 + m] = SCALE * (qpos[n * 4 + m] + pm[m]);
            }
        }
    }
}

// ---------------------------------------------------------------------------
// Kernel 2b: finish channel attention. One block per n.
// ksum[c] = sum of 64 tile-partials; logits = scale*(acq + ksum@W_ch_bot);
// softmax over dph (stride-4 groups of 64); write a_c[n][256].
// ---------------------------------------------------------------------------
__global__ __launch_bounds__(256) void k2b_ac(
    const float* __restrict__ partial,   // [1024][256]
    const float* __restrict__ acq,       // [16][256]
    const float* __restrict__ W_ch,     // [512][256]
    float* __restrict__ a_c)             // [16][256]
{
    __shared__ float ks[256], lg[256];
    const int n = blockIdx.x, t = threadIdx.x;
    float s = 0.f;
    for (int tt = 0; tt < 64; ++tt) s += partial[(n * 64 + tt) * 256 + t];
    ks[t] = s;
    __syncthreads();
    float bot = 0.f;
    for (int d = 0; d < 256; ++d) bot += ks[d] * W_ch[(256 + d) * 256 + t];
    const float L = SCALE * (acq[n * 256 + t] + bot);
    lg[t] = L;
    __syncthreads();
    const int nh = t & 3;
    float mx = -1e30f;
    for (int i = 0; i < 64; ++i) mx = fmaxf(mx, lg[i * 4 + nh]);
    float sum = 0.f;
    for (int i = 0; i < 64; ++i) sum += __expf(lg[i * 4 + nh] - mx);
    a_c[n * 256 + t] = __expf(L - mx) / sum;
}

// ---------------------------------------------------------------------------
// Kernel 2c: position softmax over the 4096 pixels, per (n, head).
// One block per (n,m); in-place on the logits buffer -> normalized a_p.
// ---------------------------------------------------------------------------
__global__ __launch_bounds__(256) void k2c_softmax_pos(float* __restrict__ lg) // [65536][4]
{
    __shared__ float r[256];
    const int n = blockIdx.x >> 2, m = blockIdx.x & 3, t = threadIdx.x;
    const int base = n * 4096;
    float v[16];
    float mx = -1e30f;
#pragma unroll
    for (int i = 0; i < 16; ++i) {
        v[i] = lg[(base + i * 256 + t) * 4 + m];
        mx = fmaxf(mx, v[i]);
    }
    r[t] = mx; __syncthreads();
    for (int s = 128; s > 0; s >>= 1) { if (t < s) r[t] = fmaxf(r[t], r[t + s]); __syncthreads(); }
    mx = r[0]; __syncthreads();
    float sum = 0.f;
#pragma unroll
    for (int i = 0; i < 16; ++i) { v[i] = __expf(v[i] - mx); sum += v[i]; }
    r[t] = sum; __syncthreads();
    for (int s = 128; s > 0; s >>= 1) { if (t < s) r[t] += r[t + s]; __syncthreads(); }
    const float rinv = 1.f / r[0];
#pragma unroll
    for (int i = 0; i < 16; ++i) lg[(base + i * 256 + t) * 4 + m] = v[i] * rinv;
}

// ---------------------------------------------------------------------------
// Kernel 3: fused output GEMM. Per block: 64 pixels x 256 out-cols, K=512.
// A-row built on the fly: d<256 -> a_c[n,d]*vc[p,d]; d>=256 -> a_p[p,nh]*vp[p,dd].
// Epilogue: *g_out + b_out, leaky 0.1.
// ---------------------------------------------------------------------------
__global__ __launch_bounds__(256) void k3_out(
    const __hip_bfloat16* __restrict__ vc, const __hip_bfloat16* __restrict__ vp,
    const float* __restrict__ a_c, const float* __restrict__ ap,
    const float* __restrict__ W_out, const float* __restrict__ g_out, const float* __restrict__ b_out,
    float* __restrict__ outp)
{
    __shared__ float Asb[16][68];
    __shared__ float Bs[16][256];
    const int t  = threadIdx.x;
    const int cx = t & 31, py = t >> 5;
    const int pix0 = blockIdx.x * 64;
    const int n = pix0 >> 12;

    float acc[8][8];
#pragma unroll
    for (int i = 0; i < 8; ++i)
#pragma unroll
        for (int j = 0; j < 8; ++j) acc[i][j] = 0.f;

    for (int k0 = 0; k0 < 512; k0 += 16) {
        __syncthreads();
#pragma unroll
        for (int q = 0; q < 4; ++q) {
            const int e = t + q * 256;
            const int r = e >> 4, kk = e & 15;
            const int d = k0 + kk;
            const int p = pix0 + r;
            float val;
            if (d < 256) {
                val = a_c[n * 256 + d] * __bfloat162float(vc[p * 256 + d]);
            } else {
                const int dd = d - 256;
                val = ap[p * 4 + (dd >> 6)] * __bfloat162float(vp[p * 256 + dd]);
            }
            Asb[kk][r] = val;
        }
#pragma unroll
        for (int rr = 0; rr < 16; ++rr)
            Bs[rr][t] = W_out[(k0 + rr) * 256 + t];
        __syncthreads();
#pragma unroll
        for (int k = 0; k < 16; ++k) {
            float a[8], b[8];
            const float4* ap4 = reinterpret_cast<const float4*>(&Asb[k][py * 8]);
            const float4 a0 = ap4[0], a1 = ap4[1];
            a[0]=a0.x; a[1]=a0.y; a[2]=a0.z; a[3]=a0.w;
            a[4]=a1.x; a[5]=a1.y; a[6]=a1.z; a[7]=a1.w;
#pragma unroll
            for (int j = 0; j < 8; ++j) b[j] = Bs[k][j * 32 + cx];
#pragma unroll
            for (int i = 0; i < 8; ++i)
#pragma unroll
                for (int j = 0; j < 8; ++j) acc[i][j] += a[i] * b[j];
        }
    }
#pragma unroll
    for (int j = 0; j < 8; ++j) {
        const int col = j * 32 + cx;
        const float g = g_out[col], bb = b_out[col];
#pragma unroll
        for (int i = 0; i < 8; ++i) {
            const int p = pix0 + py * 8 + i;
            outp[p * 256 + col] = leaky(acc[i][j] * g + bb, 0.1f);
        }
    }
}

// ---------------------------------------------------------------------------
// Launch
// ---------------------------------------------------------------------------
extern "C" void kernel_launch(void* const* d_in, const int* in_sizes, int n_in,
                              void* d_out, int out_size, void* d_ws, size_t ws_size,
                              hipStream_t stream)
{
    const float* inputs  = (const float*)d_in[0];
    const float* style   = (const float*)d_in[1];
    const float* W_dense = (const float*)d_in[2];
    const float* Wq_c = (const float*)d_in[3];
    const float* gq_c = (const float*)d_in[4];
    const float* bq_c = (const float*)d_in[5];
    const float* Wk_c = (const float*)d_in[6];
    const float* gk_c = (const float*)d_in[7];
    const float* bk_c = (const float*)d_in[8];
    const float* Wv_c = (const float*)d_in[9];
    const float* gv_c = (const float*)d_in[10];
    const float* bv_c = (const float*)d_in[11];
    const float* Wq_p = (const float*)d_in[12];
    const float* gq_p = (const float*)d_in[13];
    const float* bq_p = (const float*)d_in[14];
    const float* Wk_p = (const float*)d_in[15];
    const float* gk_p = (const float*)d_in[16];
    const float* bk_p = (const float*)d_in[17];
    const float* Wv_p = (const float*)d_in[18];
    const float* gv_p = (const float*)d_in[19];
    const float* bv_p = (const float*)d_in[20];
    const float* W_ch  = (const float*)d_in[21];
    const float* W_pos = (const float*)d_in[22];
    const float* W_out = (const float*)d_in[23];
    const float* g_out = (const float*)d_in[24];
    const float* b_out = (const float*)d_in[25];

    float* ws = (float*)d_ws;
    // workspace layout (float offsets)
    float* acq     = ws;                 //  4096
    float* qpos    = ws + 4096;          //    64
    float* a_c     = ws + 4160;          //  4096
    float* partial = ws + 8256;          // 262144  (1024 tiles x 256)
    float* logits  = ws + 270400;        // 262144  (65536 x 4) -> becomes a_p in place
    __hip_bfloat16* vcb = (__hip_bfloat16*)(ws + 532544);            // 65536x256 bf16
    __hip_bfloat16* vpb = (__hip_bfloat16*)(ws + 532544 + 8388608);  // 65536x256 bf16
    // total: 17,309,760 floats = 69.2 MB

    k1_style<<<16, 256, 0, stream>>>(style, W_dense, Wq_c, gq_c, bq_c,
                                     Wq_p, gq_p, bq_p, W_ch, W_pos, acq, qpos);

    k2_gemm<0><<<1024, 256, 0, stream>>>(inputs, Wk_c, gk_c, bk_c, nullptr, nullptr, partial, nullptr);
    k2_gemm<1><<<1024, 256, 0, stream>>>(inputs, Wv_c, gv_c, bv_c, nullptr, nullptr, nullptr, vcb);
    k2_gemm<2><<<1024, 256, 0, stream>>>(inputs, Wk_p, gk_p, bk_p, W_pos, qpos, logits, nullptr);
    k2_gemm<3><<<1024, 256, 0, stream>>>(inputs, Wv_p, gv_p, bv_p, nullptr, nullptr, nullptr, vpb);

    k2b_ac<<<16, 256, 0, stream>>>(partial, acq, W_ch, a_c);
    k2c_softmax_pos<<<64, 256, 0, stream>>>(logits);

    k3_out<<<1024, 256, 0, stream>>>(vcb, vpb, a_c, logits, W_out, g_out, b_out, (float*)d_out);
}

// Round 3
// 181.473 us; speedup vs baseline: 3.9011x; 3.9011x over previous
//
#include <hip/hip_runtime.h>
#include <hip/hip_bf16.h>

#define NB    16
#define NPIX  4096
#define PTOT  65536
#define SCALE 0.125f

typedef __attribute__((ext_vector_type(8))) short short8;
typedef __attribute__((ext_vector_type(4))) float f32x4;

__device__ __forceinline__ float leaky(float x, float a) { return x > 0.f ? x : a * x; }

__device__ __forceinline__ float bfbits2f(unsigned short u) {
    unsigned int x = ((unsigned int)u) << 16; float f;
    __builtin_memcpy(&f, &x, 4); return f;
}
__device__ __forceinline__ unsigned short f2bfbits(float f) {
    __hip_bfloat16 h = __float2bfloat16(f); unsigned short u;
    __builtin_memcpy(&u, &h, 2); return u;
}

__device__ __forceinline__ void gld16(const void* g, void* l) {
    __builtin_amdgcn_global_load_lds(
        (const __attribute__((address_space(1))) unsigned int*)g,
        (__attribute__((address_space(3))) unsigned int*)l, 16, 0, 0);
}

// ---------------------------------------------------------------------------
// Prep: inputs fp32 -> bf16  [65536][256]
// ---------------------------------------------------------------------------
__global__ __launch_bounds__(256) void kI_cvt(const float* __restrict__ in,
                                              __hip_bfloat16* __restrict__ out)
{
    const size_t stride = (size_t)gridDim.x * 256 * 8;
    for (size_t i0 = ((size_t)blockIdx.x * 256 + threadIdx.x) * 8; i0 < (size_t)PTOT * 256; i0 += stride) {
        const float4 a = *(const float4*)(in + i0);
        const float4 b = *(const float4*)(in + i0 + 4);
        short8 v;
        v[0]=(short)f2bfbits(a.x); v[1]=(short)f2bfbits(a.y); v[2]=(short)f2bfbits(a.z); v[3]=(short)f2bfbits(a.w);
        v[4]=(short)f2bfbits(b.x); v[5]=(short)f2bfbits(b.y); v[6]=(short)f2bfbits(b.z); v[7]=(short)f2bfbits(b.w);
        *(short8*)(out + i0) = v;
    }
}

// ---------------------------------------------------------------------------
// Prep: weights fp32 -> bf16, transposed to [col][k].
// blocks 0..1023: w=b>>8,c=b&255 -> WT4[w][c][k]; blocks 1024..1279: WoutT[c][512]
// ---------------------------------------------------------------------------
__global__ __launch_bounds__(256) void kW_cvt(
    const float* __restrict__ W0, const float* __restrict__ W1,
    const float* __restrict__ W2, const float* __restrict__ W3,
    const float* __restrict__ Wout,
    __hip_bfloat16* __restrict__ WT4, __hip_bfloat16* __restrict__ WoutT)
{
    const int b = blockIdx.x, t = threadIdx.x;
    if (b < 1024) {
        const int w = b >> 8, c = b & 255;
        const float* W = (w == 0) ? W0 : (w == 1) ? W1 : (w == 2) ? W2 : W3;
        WT4[((size_t)w * 256 + c) * 256 + t] = __float2bfloat16(W[t * 256 + c]);
    } else {
        const int c = b - 1024;
        WoutT[(size_t)c * 512 + t]       = __float2bfloat16(Wout[t * 256 + c]);
        WoutT[(size_t)c * 512 + t + 256] = __float2bfloat16(Wout[(t + 256) * 256 + c]);
    }
}

// ---------------------------------------------------------------------------
// Kernel 1: style path (tiny), unchanged
// ---------------------------------------------------------------------------
__global__ __launch_bounds__(256) void k1_style(
    const float* __restrict__ style, const float* __restrict__ W_dense,
    const float* __restrict__ Wq_c, const float* __restrict__ gq_c, const float* __restrict__ bq_c,
    const float* __restrict__ Wq_p, const float* __restrict__ gq_p, const float* __restrict__ bq_p,
    const float* __restrict__ W_ch, const float* __restrict__ W_pos,
    float* __restrict__ acq, float* __restrict__ qpos)
{
    __shared__ float s0[256], s1[256], qc_s[256], qp_s[256];
    const int n = blockIdx.x, t = threadIdx.x;
    s0[t] = style[n * 256 + t];
    __syncthreads();
    float acc = 0.f;
    for (int k = 0; k < 256; ++k) acc += s0[k] * W_dense[k * 256 + t];
    s1[t] = leaky(acc, 0.3f);
    __syncthreads();
    float aq = 0.f, ap = 0.f;
    for (int k = 0; k < 256; ++k) {
        const float q = s1[k];
        aq += q * Wq_c[k * 256 + t];
        ap += q * Wq_p[k * 256 + t];
    }
    qc_s[t] = leaky(aq * gq_c[t] + bq_c[t], 0.1f);
    qp_s[t] = leaky(ap * gq_p[t] + bq_p[t], 0.1f);
    __syncthreads();
    float a = 0.f;
    for (int d = 0; d < 256; ++d) a += qc_s[d] * W_ch[d * 256 + t];
    acq[n * 256 + t] = 4096.f * a;
    if (t < 4) {
        float s = 0.f;
        for (int d = 0; d < 256; ++d) s += qp_s[d] * W_pos[d * 4 + t];
        qpos[n * 4 + t] = s;
    }
}

// ---------------------------------------------------------------------------
// MFMA GEMM: M-tile 128, N=256, K=256, BK=64. 512 threads = 8 waves (2M x 4N),
// per-wave 64x64 via 4x4 frags of 16x16x32 bf16 MFMA.
// A,B tiles in LDS as [row][64k] bf16, XOR-swizzled via pre-swizzled global src.
// G: 0=kc (column-sum partials), 1=vc (bf16 store), 2=kp (pos logits), 3=vp.
// ---------------------------------------------------------------------------
template<int G>
__global__ __launch_bounds__(512, 1) void k2m(
    const __hip_bfloat16* __restrict__ Abf,   // [65536][256] bf16
    const __hip_bfloat16* __restrict__ Bt,    // [256 col][256 k] bf16 (transposed)
    const float* __restrict__ gvec, const float* __restrict__ bvec,
    const float* __restrict__ W_pos, const float* __restrict__ qpos,
    float* __restrict__ out_f, __hip_bfloat16* __restrict__ out_b)
{
    constexpr int SMSZ = (G == 1 || G == 3) ? 49152 : 61440;
    __shared__ alignas(16) char smem[SMSZ];
    char* As = smem;                 // 16 KB: [128 row][64 k] bf16 swizzled
    char* Bs = smem + 16384;         // 32 KB: [256 col][64 k] bf16 swizzled
    float* wpos_s = (float*)(smem + 49152); // G2: [256][4]
    float* sc     = (float*)(smem + 53248); // G2: [128][4][4]
    float* red    = (float*)(smem + 49152); // G0: [2][256]

    const int t = threadIdx.x, l = t & 63, w = t >> 6;
    const int wm = w >> 2, wn = w & 3;
    const int pix0 = blockIdx.x * 128;

    if constexpr (G == 2) {
        for (int e = t; e < 1024; e += 512) wpos_s[e] = W_pos[1024 + e];  // rows 256..511
    }

    f32x4 acc[4][4];
#pragma unroll
    for (int i = 0; i < 4; ++i)
#pragma unroll
        for (int j = 0; j < 4; ++j) acc[i][j] = (f32x4)0.f;

    const int cg = (l & 7) ^ ((l >> 3) & 7);   // pre-swizzled source chunk

    for (int k0 = 0; k0 < 256; k0 += 64) {
        __syncthreads();
#pragma unroll
        for (int pass = 0; pass < 2; ++pass) {   // A: 128 rows
            const int row = w * 8 + (l >> 3) + pass * 64;
            gld16(Abf + (size_t)(pix0 + row) * 256 + k0 + cg * 8,
                  As + (w * 8 + pass * 64) * 128);
        }
#pragma unroll
        for (int pass = 0; pass < 4; ++pass) {   // B: 256 cols
            const int col = w * 8 + (l >> 3) + pass * 64;
            gld16(Bt + (size_t)col * 256 + k0 + cg * 8,
                  Bs + (w * 8 + pass * 64) * 128);
        }
        __syncthreads();
#pragma unroll
        for (int ks = 0; ks < 2; ++ks) {
            short8 af[4], bfr[4];
            const int c = ks * 4 + (l >> 4);
            const int sw = ((c ^ (l & 7)) << 4);
#pragma unroll
            for (int mf = 0; mf < 4; ++mf) {
                const int row = wm * 64 + mf * 16 + (l & 15);
                af[mf] = *(const short8*)(As + row * 128 + sw);
            }
#pragma unroll
            for (int nf = 0; nf < 4; ++nf) {
                const int col = wn * 64 + nf * 16 + (l & 15);
                bfr[nf] = *(const short8*)(Bs + col * 128 + sw);
            }
#pragma unroll
            for (int mf = 0; mf < 4; ++mf)
#pragma unroll
                for (int nf = 0; nf < 4; ++nf)
                    acc[mf][nf] = __builtin_amdgcn_mfma_f32_16x16x32_bf16(af[mf], bfr[nf], acc[mf][nf], 0, 0, 0);
        }
    }

    // BN affine + LeakyReLU(0.1)
#pragma unroll
    for (int nf = 0; nf < 4; ++nf) {
        const int col = wn * 64 + nf * 16 + (l & 15);
        const float g = gvec[col], bb = bvec[col];
#pragma unroll
        for (int mf = 0; mf < 4; ++mf)
#pragma unroll
            for (int r = 0; r < 4; ++r)
                acc[mf][nf][r] = leaky(acc[mf][nf][r] * g + bb, 0.1f);
    }

    if constexpr (G == 1 || G == 3) {
#pragma unroll
        for (int mf = 0; mf < 4; ++mf)
#pragma unroll
            for (int r = 0; r < 4; ++r) {
                const int p = pix0 + wm * 64 + mf * 16 + (l >> 4) * 4 + r;
#pragma unroll
                for (int nf = 0; nf < 4; ++nf) {
                    const int col = wn * 64 + nf * 16 + (l & 15);
                    out_b[(size_t)p * 256 + col] = __float2bfloat16(acc[mf][nf][r]);
                }
            }
    } else if constexpr (G == 0) {
        float cs[4];
#pragma unroll
        for (int nf = 0; nf < 4; ++nf) {
            cs[nf] = 0.f;
#pragma unroll
            for (int mf = 0; mf < 4; ++mf)
#pragma unroll
                for (int r = 0; r < 4; ++r) cs[nf] += acc[mf][nf][r];
            float v = cs[nf];
            v += __shfl_xor(v, 16);
            v += __shfl_xor(v, 32);
            if (l < 16) red[wm * 256 + wn * 64 + nf * 16 + l] = v;
        }
        __syncthreads();
        if (t < 256) out_f[(size_t)blockIdx.x * 256 + t] = red[t] + red[256 + t];
    } else {  // G == 2: position logits
#pragma unroll
        for (int mf = 0; mf < 4; ++mf)
#pragma unroll
            for (int r = 0; r < 4; ++r) {
                const int row_l = wm * 64 + mf * 16 + (l >> 4) * 4 + r;
                float pm0 = 0.f, pm1 = 0.f, pm2 = 0.f, pm3 = 0.f;
#pragma unroll
                for (int nf = 0; nf < 4; ++nf) {
                    const int col = wn * 64 + nf * 16 + (l & 15);
                    const float v = acc[mf][nf][r];
                    pm0 += v * wpos_s[col * 4 + 0];
                    pm1 += v * wpos_s[col * 4 + 1];
                    pm2 += v * wpos_s[col * 4 + 2];
                    pm3 += v * wpos_s[col * 4 + 3];
                }
#pragma unroll
                for (int mask = 1; mask <= 8; mask <<= 1) {
                    pm0 += __shfl_xor(pm0, mask);
                    pm1 += __shfl_xor(pm1, mask);
                    pm2 += __shfl_xor(pm2, mask);
                    pm3 += __shfl_xor(pm3, mask);
                }
                if ((l & 15) == 0) {
                    float* s = &sc[(row_l * 4) * 4 + wn];
                    s[0] = pm0; s[4] = pm1; s[8] = pm2; s[12] = pm3;
                }
            }
        __syncthreads();
        {
            const int row = t >> 2, m = t & 3;
            const float sum = sc[(row * 4 + m) * 4 + 0] + sc[(row * 4 + m) * 4 + 1]
                            + sc[(row * 4 + m) * 4 + 2] + sc[(row * 4 + m) * 4 + 3];
            const int p = pix0 + row;
            out_f[(size_t)p * 4 + m] = SCALE * (qpos[(pix0 >> 12) * 4 + m] + sum);
        }
    }
}

// ---------------------------------------------------------------------------
// Kernel 2b: channel softmax (32 tiles of 128 pixels per n)
// ---------------------------------------------------------------------------
__global__ __launch_bounds__(256) void k2b_ac(
    const float* __restrict__ partial,   // [512][256]
    const float* __restrict__ acq, const float* __restrict__ W_ch,
    float* __restrict__ a_c)
{
    __shared__ float ks[256], lg[256];
    const int n = blockIdx.x, t = threadIdx.x;
    float s = 0.f;
    for (int tt = 0; tt < 32; ++tt) s += partial[(size_t)(n * 32 + tt) * 256 + t];
    ks[t] = s;
    __syncthreads();
    float bot = 0.f;
    for (int d = 0; d < 256; ++d) bot += ks[d] * W_ch[(256 + d) * 256 + t];
    const float L = SCALE * (acq[n * 256 + t] + bot);
    lg[t] = L;
    __syncthreads();
    const int nh = t & 3;
    float mx = -1e30f;
    for (int i = 0; i < 64; ++i) mx = fmaxf(mx, lg[i * 4 + nh]);
    float sum = 0.f;
    for (int i = 0; i < 64; ++i) sum += __expf(lg[i * 4 + nh] - mx);
    a_c[n * 256 + t] = __expf(L - mx) / sum;
}

// ---------------------------------------------------------------------------
// Kernel 2c: position softmax over 4096 pixels per (n, head), in place
// ---------------------------------------------------------------------------
__global__ __launch_bounds__(256) void k2c_softmax_pos(float* __restrict__ lg)
{
    __shared__ float r[256];
    const int n = blockIdx.x >> 2, m = blockIdx.x & 3, t = threadIdx.x;
    const int base = n * 4096;
    float v[16];
    float mx = -1e30f;
#pragma unroll
    for (int i = 0; i < 16; ++i) {
        v[i] = lg[(size_t)(base + i * 256 + t) * 4 + m];
        mx = fmaxf(mx, v[i]);
    }
    r[t] = mx; __syncthreads();
    for (int s = 128; s > 0; s >>= 1) { if (t < s) r[t] = fmaxf(r[t], r[t + s]); __syncthreads(); }
    mx = r[0]; __syncthreads();
    float sum = 0.f;
#pragma unroll
    for (int i = 0; i < 16; ++i) { v[i] = __expf(v[i] - mx); sum += v[i]; }
    r[t] = sum; __syncthreads();
    for (int s = 128; s > 0; s >>= 1) { if (t < s) r[t] += r[t + s]; __syncthreads(); }
    const float rinv = 1.f / r[0];
#pragma unroll
    for (int i = 0; i < 16; ++i) lg[(size_t)(base + i * 256 + t) * 4 + m] = v[i] * rinv;
}

// ---------------------------------------------------------------------------
// Kernel 3: output GEMM, K=512, MFMA. A = [a_c .* vc | a_p .* vp] built in
// reg-staging (bf16); B = WoutT [256 col][512 k] via global_load_lds.
// ---------------------------------------------------------------------------
__global__ __launch_bounds__(512, 1) void k3m(
    const __hip_bfloat16* __restrict__ vcb, const __hip_bfloat16* __restrict__ vpb,
    const float* __restrict__ a_c, const float* __restrict__ apos,
    const __hip_bfloat16* __restrict__ Bt,  // WoutT
    const float* __restrict__ g_out, const float* __restrict__ b_out,
    float* __restrict__ outp)
{
    __shared__ alignas(16) char smem[49152 + 1024];
    char* As = smem;                         // [128][64k] bf16 swizzled
    char* Bs = smem + 16384;                 // [256][64k] bf16 swizzled
    float* ac_s = (float*)(smem + 49152);    // a_c[n][256]

    const int t = threadIdx.x, l = t & 63, w = t >> 6;
    const int wm = w >> 2, wn = w & 3;
    const int pix0 = blockIdx.x * 128;
    const int n = pix0 >> 12;

    if (t < 256) ac_s[t] = a_c[n * 256 + t];

    f32x4 acc[4][4];
#pragma unroll
    for (int i = 0; i < 4; ++i)
#pragma unroll
        for (int j = 0; j < 4; ++j) acc[i][j] = (f32x4)0.f;

    const int cgB = (l & 7) ^ ((l >> 3) & 7);

    for (int k0 = 0; k0 < 512; k0 += 64) {
        __syncthreads();
        // ---- A: reg-staged construct, swizzled ds_write_b128 ----
#pragma unroll
        for (int pass = 0; pass < 2; ++pass) {
            const int row = (t >> 3) + pass * 64;      // 0..127
            const int c   = t & 7;                      // data chunk
            const int slot = c ^ (row & 7);
            const int p = pix0 + row;
            float f[8];
            if (k0 < 256) {
                const int d0 = k0 + c * 8;
                const short8 src = *(const short8*)(vcb + (size_t)p * 256 + d0);
#pragma unroll
                for (int j = 0; j < 8; ++j)
                    f[j] = bfbits2f((unsigned short)src[j]) * ac_s[d0 + j];
            } else {
                const int d0 = k0 - 256 + c * 8;
                const int h = (k0 - 256) >> 6;
                const float ap = apos[(size_t)p * 4 + h];
                const short8 src = *(const short8*)(vpb + (size_t)p * 256 + d0);
#pragma unroll
                for (int j = 0; j < 8; ++j)
                    f[j] = bfbits2f((unsigned short)src[j]) * ap;
            }
            short8 v;
#pragma unroll
            for (int j = 0; j < 8; ++j) v[j] = (short)f2bfbits(f[j]);
            *(short8*)(As + row * 128 + slot * 16) = v;
        }
        // ---- B: global_load_lds, pre-swizzled source ----
#pragma unroll
        for (int pass = 0; pass < 4; ++pass) {
            const int col = w * 8 + (l >> 3) + pass * 64;
            gld16(Bt + (size_t)col * 512 + k0 + cgB * 8,
                  Bs + (w * 8 + pass * 64) * 128);
        }
        __syncthreads();
#pragma unroll
        for (int ks = 0; ks < 2; ++ks) {
            short8 af[4], bfr[4];
            const int c = ks * 4 + (l >> 4);
            const int sw = ((c ^ (l & 7)) << 4);
#pragma unroll
            for (int mf = 0; mf < 4; ++mf) {
                const int row = wm * 64 + mf * 16 + (l & 15);
                af[mf] = *(const short8*)(As + row * 128 + sw);
            }
#pragma unroll
            for (int nf = 0; nf < 4; ++nf) {
                const int col = wn * 64 + nf * 16 + (l & 15);
                bfr[nf] = *(const short8*)(Bs + col * 128 + sw);
            }
#pragma unroll
            for (int mf = 0; mf < 4; ++mf)
#pragma unroll
                for (int nf = 0; nf < 4; ++nf)
                    acc[mf][nf] = __builtin_amdgcn_mfma_f32_16x16x32_bf16(af[mf], bfr[nf], acc[mf][nf], 0, 0, 0);
        }
    }

#pragma unroll
    for (int nf = 0; nf < 4; ++nf) {
        const int col = wn * 64 + nf * 16 + (l & 15);
        const float g = g_out[col], bb = b_out[col];
#pragma unroll
        for (int mf = 0; mf < 4; ++mf)
#pragma unroll
            for (int r = 0; r < 4; ++r) {
                const int p = pix0 + wm * 64 + mf * 16 + (l >> 4) * 4 + r;
                outp[(size_t)p * 256 + col] = leaky(acc[mf][nf][r] * g + bb, 0.1f);
            }
    }
}

// ---------------------------------------------------------------------------
// Launch
// ---------------------------------------------------------------------------
extern "C" void kernel_launch(void* const* d_in, const int* in_sizes, int n_in,
                              void* d_out, int out_size, void* d_ws, size_t ws_size,
                              hipStream_t stream)
{
    const float* inputs  = (const float*)d_in[0];
    const float* style   = (const float*)d_in[1];
    const float* W_dense = (const float*)d_in[2];
    const float* Wq_c = (const float*)d_in[3];
    const float* gq_c = (const float*)d_in[4];
    const float* bq_c = (const float*)d_in[5];
    const float* Wk_c = (const float*)d_in[6];
    const float* gk_c = (const float*)d_in[7];
    const float* bk_c = (const float*)d_in[8];
    const float* Wv_c = (const float*)d_in[9];
    const float* gv_c = (const float*)d_in[10];
    const float* bv_c = (const float*)d_in[11];
    const float* Wq_p = (const float*)d_in[12];
    const float* gq_p = (const float*)d_in[13];
    const float* bq_p = (const float*)d_in[14];
    const float* Wk_p = (const float*)d_in[15];
    const float* gk_p = (const float*)d_in[16];
    const float* bk_p = (const float*)d_in[17];
    const float* Wv_p = (const float*)d_in[18];
    const float* gv_p = (const float*)d_in[19];
    const float* bv_p = (const float*)d_in[20];
    const float* W_ch  = (const float*)d_in[21];
    const float* W_pos = (const float*)d_in[22];
    const float* W_out = (const float*)d_in[23];
    const float* g_out = (const float*)d_in[24];
    const float* b_out = (const float*)d_in[25];

    float* ws = (float*)d_ws;
    float* acq     = ws;                  //      4096
    float* qpos    = ws + 4096;           //        64
    float* a_c     = ws + 4160;           //      4096
    float* partial = ws + 8256;           //   131072 (512 x 256)
    float* logits  = ws + 139328;         //   262144 (65536 x 4) -> a_p in place
    __hip_bfloat16* in_bf = (__hip_bfloat16*)(ws + 401472);    // 65536x256
    __hip_bfloat16* vcb   = (__hip_bfloat16*)(ws + 8790080);   // 65536x256
    __hip_bfloat16* vpb   = (__hip_bfloat16*)(ws + 17178688);  // 65536x256
    __hip_bfloat16* WT4   = (__hip_bfloat16*)(ws + 25567296);  // 4x256x256 (transposed)
    __hip_bfloat16* WoutT = (__hip_bfloat16*)(ws + 25698368);  // 256x512 (transposed)
    // total 25,763,904 floats = 103 MB

    kI_cvt<<<2048, 256, 0, stream>>>(inputs, in_bf);
    kW_cvt<<<1280, 256, 0, stream>>>(Wk_c, Wv_c, Wk_p, Wv_p, W_out, WT4, WoutT);
    k1_style<<<16, 256, 0, stream>>>(style, W_dense, Wq_c, gq_c, bq_c,
                                     Wq_p, gq_p, bq_p, W_ch, W_pos, acq, qpos);

    k2m<0><<<512, 512, 0, stream>>>(in_bf, WT4,              gk_c, bk_c, nullptr, nullptr, partial, nullptr);
    k2m<1><<<512, 512, 0, stream>>>(in_bf, WT4 + 65536,      gv_c, bv_c, nullptr, nullptr, nullptr, vcb);
    k2m<2><<<512, 512, 0, stream>>>(in_bf, WT4 + 2 * 65536,  gk_p, bk_p, W_pos, qpos, logits, nullptr);
    k2m<3><<<512, 512, 0, stream>>>(in_bf, WT4 + 3 * 65536,  gv_p, bv_p, nullptr, nullptr, nullptr, vpb);

    k2b_ac<<<16, 256, 0, stream>>>(partial, acq, W_ch, a_c);
    k2c_softmax_pos<<<64, 256, 0, stream>>>(logits);

    k3m<<<512, 512, 0, stream>>>(vcb, vpb, a_c, logits, WoutT, g_out, b_out, (float*)d_out);
}

// Round 4
// 169.678 us; speedup vs baseline: 4.1723x; 1.0695x over previous
//
#include <hip/hip_runtime.h>
#include <hip/hip_bf16.h>

#define NB    16
#define NPIX  4096
#define PTOT  65536
#define SCALE 0.125f

typedef __attribute__((ext_vector_type(8))) short short8;
typedef __attribute__((ext_vector_type(4))) float f32x4;

__device__ __forceinline__ float leaky(float x, float a) { return x > 0.f ? x : a * x; }

__device__ __forceinline__ float bfbits2f(unsigned short u) {
    unsigned int x = ((unsigned int)u) << 16; float f;
    __builtin_memcpy(&f, &x, 4); return f;
}
__device__ __forceinline__ unsigned short f2bfbits(float f) {
    __hip_bfloat16 h = __float2bfloat16(f); unsigned short u;
    __builtin_memcpy(&u, &h, 2); return u;
}

__device__ __forceinline__ void gld16(const void* g, void* l) {
    __builtin_amdgcn_global_load_lds(
        (const __attribute__((address_space(1))) unsigned int*)g,
        (__attribute__((address_space(3))) unsigned int*)l, 16, 0, 0);
}

// ---------------------------------------------------------------------------
// Fused prep: blocks 0..2047 convert inputs fp32->bf16 (grid-stride);
// blocks 2048..3071: WT4[w][c][k] transposed bf16; 3072..3327: WoutT[c][512].
// ---------------------------------------------------------------------------
__global__ __launch_bounds__(256) void kIW_cvt(
    const float* __restrict__ in, __hip_bfloat16* __restrict__ out,
    const float* __restrict__ W0, const float* __restrict__ W1,
    const float* __restrict__ W2, const float* __restrict__ W3,
    const float* __restrict__ Wout,
    __hip_bfloat16* __restrict__ WT4, __hip_bfloat16* __restrict__ WoutT)
{
    const int b = blockIdx.x, t = threadIdx.x;
    if (b < 2048) {
        const size_t stride = (size_t)2048 * 256 * 8;
        for (size_t i0 = ((size_t)b * 256 + t) * 8; i0 < (size_t)PTOT * 256; i0 += stride) {
            const float4 a = *(const float4*)(in + i0);
            const float4 c = *(const float4*)(in + i0 + 4);
            short8 v;
            v[0]=(short)f2bfbits(a.x); v[1]=(short)f2bfbits(a.y); v[2]=(short)f2bfbits(a.z); v[3]=(short)f2bfbits(a.w);
            v[4]=(short)f2bfbits(c.x); v[5]=(short)f2bfbits(c.y); v[6]=(short)f2bfbits(c.z); v[7]=(short)f2bfbits(c.w);
            *(short8*)(out + i0) = v;
        }
    } else if (b < 3072) {
        const int bb = b - 2048;
        const int w = bb >> 8, c = bb & 255;
        const float* W = (w == 0) ? W0 : (w == 1) ? W1 : (w == 2) ? W2 : W3;
        WT4[((size_t)w * 256 + c) * 256 + t] = __float2bfloat16(W[t * 256 + c]);
    } else {
        const int c = b - 3072;
        WoutT[(size_t)c * 512 + t]       = __float2bfloat16(Wout[t * 256 + c]);
        WoutT[(size_t)c * 512 + t + 256] = __float2bfloat16(Wout[(t + 256) * 256 + c]);
    }
}

// ---------------------------------------------------------------------------
// Kernel 1: style path, k-parallel. 16 blocks x 1024 threads.
// thread t = (kp = t>>8 in [0,4), c = t&255). Each K=256 dot is split into
// 4 x 64-iteration partials reduced through LDS -> 4x shorter dependent chain,
// 8 loads in flight via unroll.
// ---------------------------------------------------------------------------
__global__ __launch_bounds__(1024) void k1_style(
    const float* __restrict__ style, const float* __restrict__ W_dense,
    const float* __restrict__ Wq_c, const float* __restrict__ gq_c, const float* __restrict__ bq_c,
    const float* __restrict__ Wq_p, const float* __restrict__ gq_p, const float* __restrict__ bq_p,
    const float* __restrict__ W_ch, const float* __restrict__ W_pos,
    float* __restrict__ acq, float* __restrict__ qpos)
{
    __shared__ float s0[256], s1[256], qc_s[256], qp_s[256];
    __shared__ float pa[4][256], pb[4][256];
    const int n = blockIdx.x, t = threadIdx.x;
    const int kp = t >> 8, c = t & 255;
    const int kbase = kp * 64;

    if (t < 256) s0[t] = style[n * 256 + t];
    __syncthreads();

    // stage 1: s1 = leaky(style @ W_dense, 0.3)
    {
        float a = 0.f;
#pragma unroll 8
        for (int i = 0; i < 64; ++i) a += s0[kbase + i] * W_dense[(kbase + i) * 256 + c];
        pa[kp][c] = a;
    }
    __syncthreads();
    if (t < 256) s1[t] = leaky(pa[0][t] + pa[1][t] + pa[2][t] + pa[3][t], 0.3f);
    __syncthreads();

    // stage 2: qc = cbl(s1, Wq_c), qp = cbl(s1, Wq_p)
    {
        float aq = 0.f, ap = 0.f;
#pragma unroll 8
        for (int i = 0; i < 64; ++i) {
            const float q = s1[kbase + i];
            aq += q * Wq_c[(kbase + i) * 256 + c];
            ap += q * Wq_p[(kbase + i) * 256 + c];
        }
        pa[kp][c] = aq; pb[kp][c] = ap;
    }
    __syncthreads();
    if (t < 256) {
        qc_s[t] = leaky((pa[0][t] + pa[1][t] + pa[2][t] + pa[3][t]) * gq_c[t] + bq_c[t], 0.1f);
        qp_s[t] = leaky((pb[0][t] + pb[1][t] + pb[2][t] + pb[3][t]) * gq_p[t] + bq_p[t], 0.1f);
    }
    __syncthreads();

    // stage 3a: acq = 4096 * (qc @ W_ch_top)
    {
        float a = 0.f;
#pragma unroll 8
        for (int i = 0; i < 64; ++i) a += qc_s[kbase + i] * W_ch[(kbase + i) * 256 + c];
        pa[kp][c] = a;
    }
    // stage 3b: qpos = qp @ W_pos_top  (4 outputs), wave-shuffle reduce.
    // thread t: m = t&3, dp = t>>2 in [0,256). Lanes with equal m within a wave
    // differ in bits 2..5 -> shfl_xor masks 4,8,16,32 sum the 16 dp's per wave.
    {
        float v = qp_s[t >> 2] * W_pos[(t >> 2) * 4 + (t & 3)];
        v += __shfl_xor(v, 4);
        v += __shfl_xor(v, 8);
        v += __shfl_xor(v, 16);
        v += __shfl_xor(v, 32);
        if ((t & 63) < 4) pb[0][(t >> 6) * 4 + (t & 3)] = v;  // 16 waves x 4
    }
    __syncthreads();
    if (t < 256) acq[n * 256 + t] = 4096.f * (pa[0][t] + pa[1][t] + pa[2][t] + pa[3][t]);
    if (t < 4) {
        float s = 0.f;
#pragma unroll
        for (int w = 0; w < 16; ++w) s += pb[0][w * 4 + t];
        qpos[n * 4 + t] = s;
    }
}

// ---------------------------------------------------------------------------
// MFMA GEMM: M-tile 128, N=256, K=256, BK=64. 512 threads = 8 waves (2M x 4N),
// per-wave 64x64 via 4x4 frags of 16x16x32 bf16 MFMA.
// A,B tiles in LDS as [row][64k] bf16, XOR-swizzled via pre-swizzled global src.
// G: 0=kc (column-sum partials), 1=vc (bf16 store), 2=kp (pos logits), 3=vp.
// ---------------------------------------------------------------------------
template<int G>
__global__ __launch_bounds__(512, 1) void k2m(
    const __hip_bfloat16* __restrict__ Abf,   // [65536][256] bf16
    const __hip_bfloat16* __restrict__ Bt,    // [256 col][256 k] bf16 (transposed)
    const float* __restrict__ gvec, const float* __restrict__ bvec,
    const float* __restrict__ W_pos, const float* __restrict__ qpos,
    float* __restrict__ out_f, __hip_bfloat16* __restrict__ out_b)
{
    constexpr int SMSZ = (G == 1 || G == 3) ? 49152 : 61440;
    __shared__ alignas(16) char smem[SMSZ];
    char* As = smem;                 // 16 KB: [128 row][64 k] bf16 swizzled
    char* Bs = smem + 16384;         // 32 KB: [256 col][64 k] bf16 swizzled
    float* wpos_s = (float*)(smem + 49152); // G2: [256][4]
    float* sc     = (float*)(smem + 53248); // G2: [128][4][4]
    float* red    = (float*)(smem + 49152); // G0: [2][256]

    const int t = threadIdx.x, l = t & 63, w = t >> 6;
    const int wm = w >> 2, wn = w & 3;
    const int pix0 = blockIdx.x * 128;

    if constexpr (G == 2) {
        for (int e = t; e < 1024; e += 512) wpos_s[e] = W_pos[1024 + e];  // rows 256..511
    }

    f32x4 acc[4][4];
#pragma unroll
    for (int i = 0; i < 4; ++i)
#pragma unroll
        for (int j = 0; j < 4; ++j) acc[i][j] = (f32x4)0.f;

    const int cg = (l & 7) ^ ((l >> 3) & 7);   // pre-swizzled source chunk

    for (int k0 = 0; k0 < 256; k0 += 64) {
        __syncthreads();
#pragma unroll
        for (int pass = 0; pass < 2; ++pass) {   // A: 128 rows
            const int row = w * 8 + (l >> 3) + pass * 64;
            gld16(Abf + (size_t)(pix0 + row) * 256 + k0 + cg * 8,
                  As + (w * 8 + pass * 64) * 128);
        }
#pragma unroll
        for (int pass = 0; pass < 4; ++pass) {   // B: 256 cols
            const int col = w * 8 + (l >> 3) + pass * 64;
            gld16(Bt + (size_t)col * 256 + k0 + cg * 8,
                  Bs + (w * 8 + pass * 64) * 128);
        }
        __syncthreads();
#pragma unroll
        for (int ks = 0; ks < 2; ++ks) {
            short8 af[4], bfr[4];
            const int c = ks * 4 + (l >> 4);
            const int sw = ((c ^ (l & 7)) << 4);
#pragma unroll
            for (int mf = 0; mf < 4; ++mf) {
                const int row = wm * 64 + mf * 16 + (l & 15);
                af[mf] = *(const short8*)(As + row * 128 + sw);
            }
#pragma unroll
            for (int nf = 0; nf < 4; ++nf) {
                const int col = wn * 64 + nf * 16 + (l & 15);
                bfr[nf] = *(const short8*)(Bs + col * 128 + sw);
            }
#pragma unroll
            for (int mf = 0; mf < 4; ++mf)
#pragma unroll
                for (int nf = 0; nf < 4; ++nf)
                    acc[mf][nf] = __builtin_amdgcn_mfma_f32_16x16x32_bf16(af[mf], bfr[nf], acc[mf][nf], 0, 0, 0);
        }
    }

    // BN affine + LeakyReLU(0.1)
#pragma unroll
    for (int nf = 0; nf < 4; ++nf) {
        const int col = wn * 64 + nf * 16 + (l & 15);
        const float g = gvec[col], bb = bvec[col];
#pragma unroll
        for (int mf = 0; mf < 4; ++mf)
#pragma unroll
            for (int r = 0; r < 4; ++r)
                acc[mf][nf][r] = leaky(acc[mf][nf][r] * g + bb, 0.1f);
    }

    if constexpr (G == 1 || G == 3) {
#pragma unroll
        for (int mf = 0; mf < 4; ++mf)
#pragma unroll
            for (int r = 0; r < 4; ++r) {
                const int p = pix0 + wm * 64 + mf * 16 + (l >> 4) * 4 + r;
#pragma unroll
                for (int nf = 0; nf < 4; ++nf) {
                    const int col = wn * 64 + nf * 16 + (l & 15);
                    out_b[(size_t)p * 256 + col] = __float2bfloat16(acc[mf][nf][r]);
                }
            }
    } else if constexpr (G == 0) {
        float cs[4];
#pragma unroll
        for (int nf = 0; nf < 4; ++nf) {
            cs[nf] = 0.f;
#pragma unroll
            for (int mf = 0; mf < 4; ++mf)
#pragma unroll
                for (int r = 0; r < 4; ++r) cs[nf] += acc[mf][nf][r];
            float v = cs[nf];
            v += __shfl_xor(v, 16);
            v += __shfl_xor(v, 32);
            if (l < 16) red[wm * 256 + wn * 64 + nf * 16 + l] = v;
        }
        __syncthreads();
        if (t < 256) out_f[(size_t)blockIdx.x * 256 + t] = red[t] + red[256 + t];
    } else {  // G == 2: position logits
#pragma unroll
        for (int mf = 0; mf < 4; ++mf)
#pragma unroll
            for (int r = 0; r < 4; ++r) {
                const int row_l = wm * 64 + mf * 16 + (l >> 4) * 4 + r;
                float pm0 = 0.f, pm1 = 0.f, pm2 = 0.f, pm3 = 0.f;
#pragma unroll
                for (int nf = 0; nf < 4; ++nf) {
                    const int col = wn * 64 + nf * 16 + (l & 15);
                    const float v = acc[mf][nf][r];
                    pm0 += v * wpos_s[col * 4 + 0];
                    pm1 += v * wpos_s[col * 4 + 1];
                    pm2 += v * wpos_s[col * 4 + 2];
                    pm3 += v * wpos_s[col * 4 + 3];
                }
#pragma unroll
                for (int mask = 1; mask <= 8; mask <<= 1) {
                    pm0 += __shfl_xor(pm0, mask);
                    pm1 += __shfl_xor(pm1, mask);
                    pm2 += __shfl_xor(pm2, mask);
                    pm3 += __shfl_xor(pm3, mask);
                }
                if ((l & 15) == 0) {
                    float* s = &sc[(row_l * 4) * 4 + wn];
                    s[0] = pm0; s[4] = pm1; s[8] = pm2; s[12] = pm3;
                }
            }
        __syncthreads();
        {
            const int row = t >> 2, m = t & 3;
            const float sum = sc[(row * 4 + m) * 4 + 0] + sc[(row * 4 + m) * 4 + 1]
                            + sc[(row * 4 + m) * 4 + 2] + sc[(row * 4 + m) * 4 + 3];
            const int p = pix0 + row;
            out_f[(size_t)p * 4 + m] = SCALE * (qpos[(pix0 >> 12) * 4 + m] + sum);
        }
    }
}

// ---------------------------------------------------------------------------
// Fused softmax kernel: blocks 0..15 -> channel softmax (k2b);
// blocks 16..79 -> position softmax (k2c).
// ---------------------------------------------------------------------------
__global__ __launch_bounds__(256) void k2bc(
    const float* __restrict__ partial,   // [512][256]
    const float* __restrict__ acq, const float* __restrict__ W_ch,
    float* __restrict__ a_c, float* __restrict__ lg)
{
    const int t = threadIdx.x;
    if (blockIdx.x < 16) {
        __shared__ float ks[256], lgs[256];
        const int n = blockIdx.x;
        float s = 0.f;
        for (int tt = 0; tt < 32; ++tt) s += partial[(size_t)(n * 32 + tt) * 256 + t];
        ks[t] = s;
        __syncthreads();
        float bot = 0.f;
        for (int d = 0; d < 256; ++d) bot += ks[d] * W_ch[(256 + d) * 256 + t];
        const float L = SCALE * (acq[n * 256 + t] + bot);
        lgs[t] = L;
        __syncthreads();
        const int nh = t & 3;
        float mx = -1e30f;
        for (int i = 0; i < 64; ++i) mx = fmaxf(mx, lgs[i * 4 + nh]);
        float sum = 0.f;
        for (int i = 0; i < 64; ++i) sum += __expf(lgs[i * 4 + nh] - mx);
        a_c[n * 256 + t] = __expf(L - mx) / sum;
    } else {
        __shared__ float r[256];
        const int bb = blockIdx.x - 16;
        const int n = bb >> 2, m = bb & 3;
        const int base = n * 4096;
        float v[16];
        float mx = -1e30f;
#pragma unroll
        for (int i = 0; i < 16; ++i) {
            v[i] = lg[(size_t)(base + i * 256 + t) * 4 + m];
            mx = fmaxf(mx, v[i]);
        }
        r[t] = mx; __syncthreads();
        for (int s = 128; s > 0; s >>= 1) { if (t < s) r[t] = fmaxf(r[t], r[t + s]); __syncthreads(); }
        mx = r[0]; __syncthreads();
        float sum = 0.f;
#pragma unroll
        for (int i = 0; i < 16; ++i) { v[i] = __expf(v[i] - mx); sum += v[i]; }
        r[t] = sum; __syncthreads();
        for (int s = 128; s > 0; s >>= 1) { if (t < s) r[t] += r[t + s]; __syncthreads(); }
        const float rinv = 1.f / r[0];
#pragma unroll
        for (int i = 0; i < 16; ++i) lg[(size_t)(base + i * 256 + t) * 4 + m] = v[i] * rinv;
    }
}

// ---------------------------------------------------------------------------
// Kernel 3: output GEMM, K=512, MFMA. A = [a_c .* vc | a_p .* vp] built in
// reg-staging (bf16); B = WoutT [256 col][512 k] via global_load_lds.
// ---------------------------------------------------------------------------
__global__ __launch_bounds__(512, 1) void k3m(
    const __hip_bfloat16* __restrict__ vcb, const __hip_bfloat16* __restrict__ vpb,
    const float* __restrict__ a_c, const float* __restrict__ apos,
    const __hip_bfloat16* __restrict__ Bt,  // WoutT
    const float* __restrict__ g_out, const float* __restrict__ b_out,
    float* __restrict__ outp)
{
    __shared__ alignas(16) char smem[49152 + 1024];
    char* As = smem;                         // [128][64k] bf16 swizzled
    char* Bs = smem + 16384;                 // [256][64k] bf16 swizzled
    float* ac_s = (float*)(smem + 49152);    // a_c[n][256]

    const int t = threadIdx.x, l = t & 63, w = t >> 6;
    const int wm = w >> 2, wn = w & 3;
    const int pix0 = blockIdx.x * 128;
    const int n = pix0 >> 12;

    if (t < 256) ac_s[t] = a_c[n * 256 + t];

    f32x4 acc[4][4];
#pragma unroll
    for (int i = 0; i < 4; ++i)
#pragma unroll
        for (int j = 0; j < 4; ++j) acc[i][j] = (f32x4)0.f;

    const int cgB = (l & 7) ^ ((l >> 3) & 7);

    for (int k0 = 0; k0 < 512; k0 += 64) {
        __syncthreads();
        // ---- A: reg-staged construct, swizzled ds_write_b128 ----
#pragma unroll
        for (int pass = 0; pass < 2; ++pass) {
            const int row = (t >> 3) + pass * 64;      // 0..127
            const int c   = t & 7;                      // data chunk
            const int slot = c ^ (row & 7);
            const int p = pix0 + row;
            float f[8];
            if (k0 < 256) {
                const int d0 = k0 + c * 8;
                const short8 src = *(const short8*)(vcb + (size_t)p * 256 + d0);
#pragma unroll
                for (int j = 0; j < 8; ++j)
                    f[j] = bfbits2f((unsigned short)src[j]) * ac_s[d0 + j];
            } else {
                const int d0 = k0 - 256 + c * 8;
                const int h = (k0 - 256) >> 6;
                const float ap = apos[(size_t)p * 4 + h];
                const short8 src = *(const short8*)(vpb + (size_t)p * 256 + d0);
#pragma unroll
                for (int j = 0; j < 8; ++j)
                    f[j] = bfbits2f((unsigned short)src[j]) * ap;
            }
            short8 v;
#pragma unroll
            for (int j = 0; j < 8; ++j) v[j] = (short)f2bfbits(f[j]);
            *(short8*)(As + row * 128 + slot * 16) = v;
        }
        // ---- B: global_load_lds, pre-swizzled source ----
#pragma unroll
        for (int pass = 0; pass < 4; ++pass) {
            const int col = w * 8 + (l >> 3) + pass * 64;
            gld16(Bt + (size_t)col * 512 + k0 + cgB * 8,
                  Bs + (w * 8 + pass * 64) * 128);
        }
        __syncthreads();
#pragma unroll
        for (int ks = 0; ks < 2; ++ks) {
            short8 af[4], bfr[4];
            const int c = ks * 4 + (l >> 4);
            const int sw = ((c ^ (l & 7)) << 4);
#pragma unroll
            for (int mf = 0; mf < 4; ++mf) {
                const int row = wm * 64 + mf * 16 + (l & 15);
                af[mf] = *(const short8*)(As + row * 128 + sw);
            }
#pragma unroll
            for (int nf = 0; nf < 4; ++nf) {
                const int col = wn * 64 + nf * 16 + (l & 15);
                bfr[nf] = *(const short8*)(Bs + col * 128 + sw);
            }
#pragma unroll
            for (int mf = 0; mf < 4; ++mf)
#pragma unroll
                for (int nf = 0; nf < 4; ++nf)
                    acc[mf][nf] = __builtin_amdgcn_mfma_f32_16x16x32_bf16(af[mf], bfr[nf], acc[mf][nf], 0, 0, 0);
        }
    }

#pragma unroll
    for (int nf = 0; nf < 4; ++nf) {
        const int col = wn * 64 + nf * 16 + (l & 15);
        const float g = g_out[col], bb = b_out[col];
#pragma unroll
        for (int mf = 0; mf < 4; ++mf)
#pragma unroll
            for (int r = 0; r < 4; ++r) {
                const int p = pix0 + wm * 64 + mf * 16 + (l >> 4) * 4 + r;
                outp[(size_t)p * 256 + col] = leaky(acc[mf][nf][r] * g + bb, 0.1f);
            }
    }
}

// ---------------------------------------------------------------------------
// Launch
// ---------------------------------------------------------------------------
extern "C" void kernel_launch(void* const* d_in, const int* in_sizes, int n_in,
                              void* d_out, int out_size, void* d_ws, size_t ws_size,
                              hipStream_t stream)
{
    const float* inputs  = (const float*)d_in[0];
    const float* style   = (const float*)d_in[1];
    const float* W_dense = (const float*)d_in[2];
    const float* Wq_c = (const float*)d_in[3];
    const float* gq_c = (const float*)d_in[4];
    const float* bq_c = (const float*)d_in[5];
    const float* Wk_c = (const float*)d_in[6];
    const float* gk_c = (const float*)d_in[7];
    const float* bk_c = (const float*)d_in[8];
    const float* Wv_c = (const float*)d_in[9];
    const float* gv_c = (const float*)d_in[10];
    const float* bv_c = (const float*)d_in[11];
    const float* Wq_p = (const float*)d_in[12];
    const float* gq_p = (const float*)d_in[13];
    const float* bq_p = (const float*)d_in[14];
    const float* Wk_p = (const float*)d_in[15];
    const float* gk_p = (const float*)d_in[16];
    const float* bk_p = (const float*)d_in[17];
    const float* Wv_p = (const float*)d_in[18];
    const float* gv_p = (const float*)d_in[19];
    const float* bv_p = (const float*)d_in[20];
    const float* W_ch  = (const float*)d_in[21];
    const float* W_pos = (const float*)d_in[22];
    const float* W_out = (const float*)d_in[23];
    const float* g_out = (const float*)d_in[24];
    const float* b_out = (const float*)d_in[25];

    float* ws = (float*)d_ws;
    float* acq     = ws;                  //      4096
    float* qpos    = ws + 4096;           //        64
    float* a_c     = ws + 4160;           //      4096
    float* partial = ws + 8256;           //   131072 (512 x 256)
    float* logits  = ws + 139328;         //   262144 (65536 x 4) -> a_p in place
    __hip_bfloat16* in_bf = (__hip_bfloat16*)(ws + 401472);    // 65536x256
    __hip_bfloat16* vcb   = (__hip_bfloat16*)(ws + 8790080);   // 65536x256
    __hip_bfloat16* vpb   = (__hip_bfloat16*)(ws + 17178688);  // 65536x256
    __hip_bfloat16* WT4   = (__hip_bfloat16*)(ws + 25567296);  // 4x256x256 (transposed)
    __hip_bfloat16* WoutT = (__hip_bfloat16*)(ws + 25698368);  // 256x512 (transposed)
    // total 25,763,904 floats = 103 MB

    kIW_cvt<<<3328, 256, 0, stream>>>(inputs, in_bf, Wk_c, Wv_c, Wk_p, Wv_p, W_out, WT4, WoutT);
    k1_style<<<16, 1024, 0, stream>>>(style, W_dense, Wq_c, gq_c, bq_c,
                                      Wq_p, gq_p, bq_p, W_ch, W_pos, acq, qpos);

    k2m<0><<<512, 512, 0, stream>>>(in_bf, WT4,              gk_c, bk_c, nullptr, nullptr, partial, nullptr);
    k2m<1><<<512, 512, 0, stream>>>(in_bf, WT4 + 65536,      gv_c, bv_c, nullptr, nullptr, nullptr, vcb);
    k2m<2><<<512, 512, 0, stream>>>(in_bf, WT4 + 2 * 65536,  gk_p, bk_p, W_pos, qpos, logits, nullptr);
    k2m<3><<<512, 512, 0, stream>>>(in_bf, WT4 + 3 * 65536,  gv_p, bv_p, nullptr, nullptr, nullptr, vpb);

    k2bc<<<80, 256, 0, stream>>>(partial, acq, W_ch, a_c, logits);

    k3m<<<512, 512, 0, stream>>>(vcb, vpb, a_c, logits, WoutT, g_out, b_out, (float*)d_out);
}